// Round 2
// baseline (1134.668 us; speedup 1.0000x reference)
//
#include <hip/hip_runtime.h>
#include <cmath>
#include <cstdint>

// B=16, S=256, H=768, L=37, Y=2S=512.
// d_out = [loss(1)] [rel_preds 16*256*512*37] [arc_preds 16*256*512]  (fp32)
//
// Pipeline (all bf16-MFMA, fp32 accumulate):
//   deps  = segment-mean(hidden, word_starts)            (fp32 -> bf16)
//   xa    = [deps | 1]   padded K=800                    (bf16, rows b*S+x)
//   yrb   = [hidden;deps | 1] padded K=800               (bf16, rows b*Y+y)
//   A1    = xa @ W_arc                                   (GEMM, bf16 out)
//   arc   = A1 @ heads^T  (heads = yrb cols 0..767)      (GEMM, fp32 out)
//   M     = xa @ W_rel[o]  (j padded to 896)             (GEMM1, bf16 out)
//   rel[b,x,y,o] = M[b,x,o,:] . yrb[b,y,:]               (GEMM2, fp32 out)
//   loss  = masked mean of arc/rel log-softmax picks
// All GEMM tiles are exact (padded dims), no bounds checks in hot loops.

#define NB 16
#define SS 256
#define HH 768
#define LLn 37
#define YY 512
#define KP 800   // padded contraction dim (H+1=769 -> 800 = 25*32)
#define JP 896   // padded W_rel j dim (769 -> 7*128)

static const long long REL_ELEMS = (long long)NB * SS * YY * LLn; // 77594624
static const long long ARC_ELEMS = (long long)NB * SS * YY;       // 2097152

typedef __bf16 bf16_t;
typedef __bf16 bf16x8 __attribute__((ext_vector_type(8)));
typedef float f32x4 __attribute__((ext_vector_type(4)));

__device__ __forceinline__ void async_copy16(const void* g, void* l) {
  // global -> LDS direct DMA, 16B per lane, dest = wave-uniform base + lane*16
  __builtin_amdgcn_global_load_lds((__attribute__((address_space(1))) void*)(g),
                                   (__attribute__((address_space(3))) void*)(l),
                                   16, 0, 0);
}

// ---------------- prep kernels ----------------

__global__ void count_valid(const int* __restrict__ word_starts,
                            int* __restrict__ n_valid, float* __restrict__ lossacc) {
  __shared__ int cnt;
  if (threadIdx.x == 0) cnt = 0;
  __syncthreads();
  const int b = blockIdx.x;
  if (word_starts[b * SS + threadIdx.x] != 0) atomicAdd(&cnt, 1);
  __syncthreads();
  if (threadIdx.x == 0) {
    n_valid[b] = cnt;
    if (b == 0) { lossacc[0] = 0.f; lossacc[1] = 0.f; }
  }
}

// hidden rows -> yrb rows y<256 (bf16, +ones col, zero pad)
__global__ void hid_rows(const float* __restrict__ hidden, bf16_t* __restrict__ yrb) {
  const long long r = blockIdx.x;            // b*256+y
  const int b = (int)(r >> 8), y = (int)(r & 255);
  const float* src = hidden + r * HH;
  bf16_t* dst = yrb + ((long long)b * YY + y) * KP;
  const int t = threadIdx.x;
  for (int h = t; h < HH; h += 256) dst[h] = (bf16_t)src[h];
  if (t < KP - HH) dst[HH + t] = (t == 0) ? (bf16_t)1.0f : (bf16_t)0.0f;
}

// segment means -> xa_p rows and yrb rows y>=256
__global__ void build_deps(const float* __restrict__ hidden, const int* __restrict__ word_starts,
                           const int* __restrict__ n_valid,
                           bf16_t* __restrict__ xa_p, bf16_t* __restrict__ yrb) {
  const int x = blockIdx.x, b = blockIdx.y, t = threadIdx.x;
  const int nv = n_valid[b];
  const bool valid = (x + 1) < nv;
  int start = word_starts[b * SS + x];
  int end = (x + 1 < SS) ? word_starts[b * SS + x + 1] : 0;
  start = min(max(start, 0), SS); end = min(max(end, 0), SS);
  const int len = max(end - start, 1);
  const float inv = 1.0f / (float)len;
  const float* hb = hidden + (long long)b * SS * HH;
  bf16_t* xr = xa_p + (long long)(b * SS + x) * KP;
  bf16_t* yr = yrb + ((long long)b * YY + SS + x) * KP;
  for (int h = t; h < HH; h += 256) {
    float s = 0.f;
    if (valid) for (int tt = start; tt < end; ++tt) s += hb[(long long)tt * HH + h];
    const bf16_t bv = (bf16_t)(valid ? s * inv : 0.f);
    xr[h] = bv; yr[h] = bv;
  }
  if (t < KP - HH) {
    const bf16_t v = (t == 0) ? (bf16_t)1.0f : (bf16_t)0.0f;
    xr[HH + t] = v; yr[HH + t] = v;
  }
}

// W_arc [769,768] fp32 -> Wab [768][800] bf16 transposed (Wab[j][i] = W_arc[i][j])
__global__ void conv_warc(const float* __restrict__ W, bf16_t* __restrict__ Wab) {
  __shared__ float tbuf[32][33];
  const int i0 = blockIdx.x * 32, j0 = blockIdx.y * 32;
  const int tx = threadIdx.x, ty = threadIdx.y;   // 32x8
  for (int rr = 0; rr < 32; rr += 8) {
    const int i = i0 + ty + rr, j = j0 + tx;
    tbuf[ty + rr][tx] = (i < HH + 1) ? W[(long long)i * HH + j] : 0.f;
  }
  __syncthreads();
  for (int rr = 0; rr < 32; rr += 8) {
    const int j = j0 + ty + rr, i = i0 + tx;
    Wab[(long long)j * KP + i] = (bf16_t)tbuf[tx][ty + rr];
  }
}

// W_rel [o][769][769] fp32 -> Wbc [z][896][800] bf16 transposed (Wbc[z][j][i] = W_rel[o0+z][i][j])
__global__ void conv_wrel(const float* __restrict__ W, bf16_t* __restrict__ Wb, int o0) {
  __shared__ float tbuf[32][33];
  const int o = o0 + blockIdx.z;
  const int i0 = blockIdx.x * 32, j0 = blockIdx.y * 32;
  const int tx = threadIdx.x, ty = threadIdx.y;   // 32x8
  const float* Wo = W + (long long)o * (HH + 1) * (HH + 1);
  for (int rr = 0; rr < 32; rr += 8) {
    const int i = i0 + ty + rr, j = j0 + tx;
    tbuf[ty + rr][tx] = (i < HH + 1 && j < HH + 1) ? Wo[(long long)i * (HH + 1) + j] : 0.f;
  }
  __syncthreads();
  bf16_t* Wbo = Wb + (long long)blockIdx.z * JP * KP;
  for (int rr = 0; rr < 32; rr += 8) {
    const int j = j0 + ty + rr, i = i0 + tx;
    Wbo[(long long)j * KP + i] = (bf16_t)tbuf[tx][ty + rr];
  }
}

// ---------------- GEMM: C = A * B^T, 128x128 tile, bf16 MFMA 16x16x32 ----------------
// A: rows of length K (stride lda), B: rows of length K (stride ldb), K % 32 == 0.
// mode 0: store bf16 to Cb + z*sCz + row*ldc + col
// mode 1: store fp32 to Cf + z*sCz + row*ldc + col
// mode 2: rel output; col n -> (x=n/OC, o=o0+n%OC); addr = z*sCz + x*(YY*LLn) + row*LLn + o

__global__ __launch_bounds__(256)
void gemm_bt(const bf16_t* __restrict__ A, long long sAz, int lda,
             const bf16_t* __restrict__ B, long long sBz, int ldb,
             int K,
             float* __restrict__ Cf, bf16_t* __restrict__ Cb,
             long long sCz, int ldc,
             int mode, int OC, int o0) {
  __shared__ __align__(16) bf16_t As[128 * 32];
  __shared__ __align__(16) bf16_t Bs[128 * 32];
  const int tid = threadIdx.x;
  const int w = tid >> 6;          // wave 0..3
  const int lane = tid & 63;
  const int z = blockIdx.z;
  const long long row0 = (long long)blockIdx.y * 128;
  const long long col0 = (long long)blockIdx.x * 128;
  const bf16_t* Ab = A + z * sAz + row0 * lda;
  const bf16_t* Bb = B + z * sBz + col0 * ldb;

  // staging: wave w fills rows [w*32, w*32+32) of As and Bs, 2 x 16-row DMA each
  const int r_in = lane >> 2;           // 0..15
  const int kofs = (lane & 3) * 8;      // elems
  const bf16_t* gA0 = Ab + (long long)(w * 32 + r_in) * lda + kofs;
  const bf16_t* gB0 = Bb + (long long)(w * 32 + r_in) * ldb + kofs;
  const bf16_t* gA1 = gA0 + 16ll * lda;
  const bf16_t* gB1 = gB0 + 16ll * ldb;
  bf16_t* lA0 = &As[(w * 32) * 32];
  bf16_t* lA1 = &As[(w * 32 + 16) * 32];
  bf16_t* lB0 = &Bs[(w * 32) * 32];
  bf16_t* lB1 = &Bs[(w * 32 + 16) * 32];

  f32x4 acc[4][4];
  #pragma unroll
  for (int i = 0; i < 4; i++)
    #pragma unroll
    for (int j = 0; j < 4; j++)
      #pragma unroll
      for (int e = 0; e < 4; e++) acc[i][j][e] = 0.f;

  const int wm = (w >> 1) * 64, wn = (w & 1) * 64;  // wave's 64x64 quadrant
  const int fr = lane & 15;                          // frag row/col index
  const int fq = lane >> 4;                          // quad
  const int aoff = fq * 8;                           // frag k offset

  for (int k0 = 0; k0 < K; k0 += 32) {
    async_copy16(gA0 + k0, lA0);
    async_copy16(gA1 + k0, lA1);
    async_copy16(gB0 + k0, lB0);
    async_copy16(gB1 + k0, lB1);
    __syncthreads();
    bf16x8 af[4], bfr[4];
    #pragma unroll
    for (int t = 0; t < 4; t++) af[t]  = *(const bf16x8*)&As[(wm + t * 16 + fr) * 32 + aoff];
    #pragma unroll
    for (int t = 0; t < 4; t++) bfr[t] = *(const bf16x8*)&Bs[(wn + t * 16 + fr) * 32 + aoff];
    #pragma unroll
    for (int tm = 0; tm < 4; tm++)
      #pragma unroll
      for (int tn = 0; tn < 4; tn++)
        acc[tm][tn] = __builtin_amdgcn_mfma_f32_16x16x32_bf16(af[tm], bfr[tn], acc[tm][tn], 0, 0, 0);
    __syncthreads();
  }

  // epilogue: C element (row = fq*4 + r, col = fr) within each 16x16 tile
  const int er = fq * 4;
  #pragma unroll
  for (int tm = 0; tm < 4; tm++) {
    #pragma unroll
    for (int tn = 0; tn < 4; tn++) {
      const int rl = wm + tm * 16 + er;
      const long long col = col0 + wn + tn * 16 + fr;
      if (mode == 0) {
        bf16_t* dst = Cb + z * sCz + col;
        #pragma unroll
        for (int r = 0; r < 4; r++)
          dst[(row0 + rl + r) * (long long)ldc] = (bf16_t)acc[tm][tn][r];
      } else if (mode == 1) {
        float* dst = Cf + z * sCz + col;
        #pragma unroll
        for (int r = 0; r < 4; r++)
          dst[(row0 + rl + r) * (long long)ldc] = acc[tm][tn][r];
      } else {
        const int n = (int)col;
        const int x = n / OC;
        const int o = o0 + (n - x * OC);
        float* dst = Cf + z * sCz + (long long)x * (YY * LLn) + o;
        #pragma unroll
        for (int r = 0; r < 4; r++)
          dst[(row0 + rl + r) * (long long)LLn] = acc[tm][tn][r];
      }
    }
  }
}

// ---------------- loss ----------------

__device__ __forceinline__ float wave_max(float v) {
  #pragma unroll
  for (int off = 32; off > 0; off >>= 1) v = fmaxf(v, __shfl_xor(v, off));
  return v;
}
__device__ __forceinline__ float wave_sum(float v) {
  #pragma unroll
  for (int off = 32; off > 0; off >>= 1) v += __shfl_xor(v, off);
  return v;
}

__global__ void loss_kernel(const float* __restrict__ arc, const float* __restrict__ rel,
                            const int* __restrict__ la, const int* __restrict__ lr,
                            float* __restrict__ acc) {
  const int r = blockIdx.x;        // b*S+x
  const int lane = threadIdx.x;    // 64
  const int lab = la[r];
  const float* ar = arc + (long long)r * YY;
  float v[8]; float m = -INFINITY;
  #pragma unroll
  for (int i = 0; i < 8; i++) { v[i] = ar[lane + 64 * i]; m = fmaxf(m, v[i]); }
  m = wave_max(m);
  float s = 0.f;
  #pragma unroll
  for (int i = 0; i < 8; i++) s += expf(v[i] - m);
  s = wave_sum(s);
  const float lse_a = m + logf(s);
  const int safe = lab < 0 ? 0 : (lab > YY - 1 ? YY - 1 : lab);
  const float* rr = rel + ((long long)r * YY + safe) * LLn;
  const float rv = (lane < LLn) ? rr[lane] : -INFINITY;
  const float m2 = wave_max(rv);
  const float s2 = wave_sum((lane < LLn) ? expf(rv - m2) : 0.f);
  const float lse_r = m2 + logf(s2);
  if (lane == 0 && lab != 0) {
    const float ll = (ar[safe] - lse_a) + (rr[lr[r]] - lse_r);
    atomicAdd(&acc[0], ll);
    atomicAdd(&acc[1], 1.f);
  }
}

__global__ void finalize(const float* __restrict__ acc, float* __restrict__ out) {
  out[0] = -acc[0] / acc[1];
}

// ---------------- launch ----------------

extern "C" void kernel_launch(void* const* d_in, const int* in_sizes, int n_in,
                              void* d_out, int out_size, void* d_ws, size_t ws_size,
                              hipStream_t stream) {
  (void)in_sizes; (void)n_in; (void)out_size;
  const float* hidden      = (const float*)d_in[0];
  const float* W_arc       = (const float*)d_in[1];
  const float* W_rel       = (const float*)d_in[2];
  const int* word_starts   = (const int*)d_in[3];
  const int* labels_arcs   = (const int*)d_in[4];
  const int* labels_rels   = (const int*)d_in[5];

  float* out = (float*)d_out;
  float* rel_out = out + 1;
  float* arc_out = rel_out + REL_ELEMS;

  char* ws = (char*)d_ws;
  int* n_valid = (int*)ws;                    // 16 ints
  float* lossacc = (float*)(ws + 64);         // 2 floats
  bf16_t* xa_p = (bf16_t*)(ws + 256);                 // [4096][800]
  bf16_t* yrb  = xa_p + (size_t)NB * SS * KP;         // [16][512][800]
  bf16_t* Wab  = yrb + (size_t)NB * YY * KP;          // [768][800]
  bf16_t* A1   = Wab + (size_t)HH * KP;               // [4096][768]
  bf16_t* Wbc  = A1 + (size_t)NB * SS * HH;           // [OC][896][800]

  const size_t fixedB = 256 + 2 * ((size_t)NB * SS * KP + (size_t)NB * YY * KP +
                                   (size_t)HH * KP + (size_t)NB * SS * HH);
  const size_t perOC = 2 * ((size_t)JP * KP + (size_t)NB * SS * JP);
  int OC = 1;
  if (ws_size > fixedB + perOC) {
    const size_t m = (ws_size - fixedB) / perOC;
    OC = (m > (size_t)LLn) ? LLn : (int)m;
  }
  bf16_t* M_p = Wbc + (size_t)OC * JP * KP;           // [4096][OC][896]

  count_valid<<<NB, SS, 0, stream>>>(word_starts, n_valid, lossacc);
  hid_rows<<<NB * SS, 256, 0, stream>>>(hidden, yrb);
  build_deps<<<dim3(SS, NB), 256, 0, stream>>>(hidden, word_starts, n_valid, xa_p, yrb);
  conv_warc<<<dim3(25, 24), dim3(32, 8), 0, stream>>>(W_arc, Wab);

  // A1 = xa @ W_arc : [4096 x 768], K=800
  gemm_bt<<<dim3(6, 32, 1), 256, 0, stream>>>(xa_p, 0, KP, Wab, 0, KP, KP,
                                              nullptr, A1, 0, HH, 0, 0, 0);
  // arc_preds[b,x,y] = A1 . heads^T, K=768 (yrb cols 0..767)
  gemm_bt<<<dim3(4, 2, NB), 256, 0, stream>>>(A1, (long long)SS * HH, HH,
                                              yrb, (long long)YY * KP, KP, HH,
                                              arc_out, nullptr, (long long)SS * YY, YY, 1, 0, 0);

  for (int o0 = 0; o0 < LLn; o0 += OC) {
    const int oc = (LLn - o0 < OC) ? (LLn - o0) : OC;
    conv_wrel<<<dim3(25, 28, oc), dim3(32, 8), 0, stream>>>(W_rel, Wbc, o0);
    // M[b,x,o,j] = xa . W_rel[o]^T(j,i), K=800, N=896(j)
    gemm_bt<<<dim3(7, 32, oc), 256, 0, stream>>>(xa_p, 0, KP,
                                                 Wbc, (long long)JP * KP, KP, KP,
                                                 nullptr, M_p, JP, oc * JP, 0, 0, 0);
    // rel[b,x,y,o] = yrb[b,y,:] . M[b,x,o,:], K=800, N=(x,o)=256*oc
    gemm_bt<<<dim3(2 * oc, 4, NB), 256, 0, stream>>>(yrb, (long long)YY * KP, KP,
                                                     M_p, (long long)SS * oc * JP, JP, KP,
                                                     rel_out, nullptr, (long long)SS * YY * LLn,
                                                     0, 2, oc, o0);
  }

  loss_kernel<<<NB * SS, 64, 0, stream>>>(arc_out, rel_out, labels_arcs, labels_rels, lossacc);
  finalize<<<1, 1, 0, stream>>>(lossacc, out);
}

// Round 3
// 1082.234 us; speedup vs baseline: 1.0484x; 1.0484x over previous
//
#include <hip/hip_runtime.h>
#include <cmath>
#include <cstdint>

// B=16, S=256, H=768, L=37, Y=2S=512.
// d_out = [loss(1)] [rel_preds 16*256*512*37] [arc_preds 16*256*512]  (fp32)
//
// Pipeline (bf16 MFMA, fp32 accum):
//   xa    = [deps | 1 | 0pad]      bf16 [4096][800]
//   yrb   = [hidden;deps | 1 | 0]  bf16 [16][512][800]
//   A1    = xa @ W_arc             -> arc = A1 @ heads^T
//   bias2 = xa @ W_rel[:,:,768]    (the j=768 slice that hits yr's ones col)
//   M     = xa @ W_rel[o]^T (j<768 only, exact 6x128 tiles)  [4096][oc][768]
//   rel   = M . yrb[:, :768] + bias2   (epilogue restaged via LDS -> coalesced)
//   loss  = masked mean of log-softmax picks

#define NB 16
#define SS 256
#define HH 768
#define LLn 37
#define YY 512
#define KP 800   // padded contraction (769 -> 800)
#define JR 768   // W_rel j dim computed by GEMM1 (769th slice -> bias2)

static const long long REL_ELEMS = (long long)NB * SS * YY * LLn;

typedef __bf16 bf16_t;
typedef __bf16 bf16x8 __attribute__((ext_vector_type(8)));
typedef float f32x4 __attribute__((ext_vector_type(4)));

__device__ __forceinline__ void async_copy16(const void* g, void* l) {
  __builtin_amdgcn_global_load_lds((__attribute__((address_space(1))) void*)(g),
                                   (__attribute__((address_space(3))) void*)(l),
                                   16, 0, 0);
}

// ---------------- prep kernels ----------------

__global__ void count_valid(const int* __restrict__ word_starts,
                            int* __restrict__ n_valid, float* __restrict__ lossacc) {
  __shared__ int cnt;
  if (threadIdx.x == 0) cnt = 0;
  __syncthreads();
  const int b = blockIdx.x;
  if (word_starts[b * SS + threadIdx.x] != 0) atomicAdd(&cnt, 1);
  __syncthreads();
  if (threadIdx.x == 0) {
    n_valid[b] = cnt;
    if (b == 0) { lossacc[0] = 0.f; lossacc[1] = 0.f; }
  }
}

__global__ void hid_rows(const float* __restrict__ hidden, bf16_t* __restrict__ yrb) {
  const long long r = blockIdx.x;            // b*256+y
  const int b = (int)(r >> 8), y = (int)(r & 255);
  const float* src = hidden + r * HH;
  bf16_t* dst = yrb + ((long long)b * YY + y) * KP;
  const int t = threadIdx.x;
  for (int h = t; h < HH; h += 256) dst[h] = (bf16_t)src[h];
  if (t < KP - HH) dst[HH + t] = (t == 0) ? (bf16_t)1.0f : (bf16_t)0.0f;
}

__global__ void build_deps(const float* __restrict__ hidden, const int* __restrict__ word_starts,
                           const int* __restrict__ n_valid,
                           bf16_t* __restrict__ xa_p, bf16_t* __restrict__ yrb) {
  const int x = blockIdx.x, b = blockIdx.y, t = threadIdx.x;
  const int nv = n_valid[b];
  const bool valid = (x + 1) < nv;
  int start = word_starts[b * SS + x];
  int end = (x + 1 < SS) ? word_starts[b * SS + x + 1] : 0;
  start = min(max(start, 0), SS); end = min(max(end, 0), SS);
  const int len = max(end - start, 1);
  const float inv = 1.0f / (float)len;
  const float* hb = hidden + (long long)b * SS * HH;
  bf16_t* xr = xa_p + (long long)(b * SS + x) * KP;
  bf16_t* yr = yrb + ((long long)b * YY + SS + x) * KP;
  for (int h = t; h < HH; h += 256) {
    float s = 0.f;
    if (valid) for (int tt = start; tt < end; ++tt) s += hb[(long long)tt * HH + h];
    const bf16_t bv = (bf16_t)(valid ? s * inv : 0.f);
    xr[h] = bv; yr[h] = bv;
  }
  if (t < KP - HH) {
    const bf16_t v = (t == 0) ? (bf16_t)1.0f : (bf16_t)0.0f;
    xr[HH + t] = v; yr[HH + t] = v;
  }
}

// W_arc [769,768] fp32 -> Wab [768][800] bf16 transposed
__global__ void conv_warc(const float* __restrict__ W, bf16_t* __restrict__ Wab) {
  __shared__ float tbuf[32][33];
  const int i0 = blockIdx.x * 32, j0 = blockIdx.y * 32;
  const int tx = threadIdx.x, ty = threadIdx.y;   // 32x8
  for (int rr = 0; rr < 32; rr += 8) {
    const int i = i0 + ty + rr, j = j0 + tx;
    tbuf[ty + rr][tx] = (i < HH + 1) ? W[(long long)i * HH + j] : 0.f;
  }
  __syncthreads();
  for (int rr = 0; rr < 32; rr += 8) {
    const int j = j0 + ty + rr, i = i0 + tx;
    Wab[(long long)j * KP + i] = (bf16_t)tbuf[tx][ty + rr];
  }
}

// W_rel [o][769][769] fp32 -> Wbc [z][768][800] bf16 transposed (j<768 only)
__global__ void conv_wrel(const float* __restrict__ W, bf16_t* __restrict__ Wb, int o0) {
  __shared__ float tbuf[32][33];
  const int o = o0 + blockIdx.z;
  const int i0 = blockIdx.x * 32, j0 = blockIdx.y * 32;   // i: 25 blocks, j: 24 blocks
  const int tx = threadIdx.x, ty = threadIdx.y;           // 32x8
  const float* Wo = W + (long long)o * (HH + 1) * (HH + 1);
  for (int rr = 0; rr < 32; rr += 8) {
    const int i = i0 + ty + rr, j = j0 + tx;
    tbuf[ty + rr][tx] = (i < HH + 1) ? Wo[(long long)i * (HH + 1) + j] : 0.f;
  }
  __syncthreads();
  bf16_t* Wbo = Wb + (long long)blockIdx.z * JR * KP;
  for (int rr = 0; rr < 32; rr += 8) {
    const int j = j0 + ty + rr, i = i0 + tx;
    Wbo[(long long)j * KP + i] = (bf16_t)tbuf[tx][ty + rr];
  }
}

// Wb768[o][i] = W_rel[o][i][768] (o<37,i<769), else 0.  [128][800] bf16
__global__ void build_wb768(const float* __restrict__ W, bf16_t* __restrict__ Wb768) {
  const int o = blockIdx.x;
  bf16_t* dst = Wb768 + (long long)o * KP;
  for (int i = threadIdx.x; i < KP; i += 256) {
    float v = 0.f;
    if (o < LLn && i < HH + 1)
      v = W[(long long)o * (HH + 1) * (HH + 1) + (long long)i * (HH + 1) + HH];
    dst[i] = (bf16_t)v;
  }
}

// ---------------- GEMM: C = A * B^T, 128x128 tile, bf16 MFMA 16x16x32 ----------------
// MODE 0: bf16 out at Cb + z*sCz + row*ldc + col
// MODE 1: fp32 out at Cf + z*sCz + row*ldc + col
// MODE 2: rel out; col n -> (x=n/OC, o=o0+n%OC); LDS-restaged coalesced stores + bias2

template<int MODE>
__global__ __launch_bounds__(256)
void gemm_bt(const bf16_t* __restrict__ A, long long sAz, int lda,
             const bf16_t* __restrict__ B, long long sBz, int ldb,
             int K,
             float* __restrict__ Cf, bf16_t* __restrict__ Cb,
             long long sCz, int ldc,
             int OC, int o0, const float* __restrict__ bias2) {
  __shared__ __align__(16) char smem_raw[16896];   // As(8K)+Bs(8K); epilogue ebuf 32x132 f32
  bf16_t* As = (bf16_t*)smem_raw;
  bf16_t* Bs = (bf16_t*)(smem_raw + 8192);
  const int tid = threadIdx.x;
  const int w = tid >> 6;
  const int lane = tid & 63;
  const int z = blockIdx.z;
  const long long row0 = (long long)blockIdx.y * 128;
  const long long col0 = (long long)blockIdx.x * 128;
  const bf16_t* Ab = A + z * sAz + row0 * lda;
  const bf16_t* Bb = B + z * sBz + col0 * ldb;

  const int r_in = lane >> 2;
  const int kofs = (lane & 3) * 8;
  const bf16_t* gA0 = Ab + (long long)(w * 32 + r_in) * lda + kofs;
  const bf16_t* gB0 = Bb + (long long)(w * 32 + r_in) * ldb + kofs;
  const bf16_t* gA1 = gA0 + 16ll * lda;
  const bf16_t* gB1 = gB0 + 16ll * ldb;
  bf16_t* lA0 = &As[(w * 32) * 32];
  bf16_t* lA1 = &As[(w * 32 + 16) * 32];
  bf16_t* lB0 = &Bs[(w * 32) * 32];
  bf16_t* lB1 = &Bs[(w * 32 + 16) * 32];

  f32x4 acc[4][4];
  #pragma unroll
  for (int i = 0; i < 4; i++)
    #pragma unroll
    for (int j = 0; j < 4; j++)
      #pragma unroll
      for (int e = 0; e < 4; e++) acc[i][j][e] = 0.f;

  const int wm = (w >> 1) * 64, wn = (w & 1) * 64;
  const int fr = lane & 15;
  const int fq = lane >> 4;
  const int aoff = fq * 8;

  for (int k0 = 0; k0 < K; k0 += 32) {
    async_copy16(gA0 + k0, lA0);
    async_copy16(gA1 + k0, lA1);
    async_copy16(gB0 + k0, lB0);
    async_copy16(gB1 + k0, lB1);
    __syncthreads();
    bf16x8 af[4], bfr[4];
    #pragma unroll
    for (int t = 0; t < 4; t++) af[t]  = *(const bf16x8*)&As[(wm + t * 16 + fr) * 32 + aoff];
    #pragma unroll
    for (int t = 0; t < 4; t++) bfr[t] = *(const bf16x8*)&Bs[(wn + t * 16 + fr) * 32 + aoff];
    #pragma unroll
    for (int tm = 0; tm < 4; tm++)
      #pragma unroll
      for (int tn = 0; tn < 4; tn++)
        acc[tm][tn] = __builtin_amdgcn_mfma_f32_16x16x32_bf16(af[tm], bfr[tn], acc[tm][tn], 0, 0, 0);
    __syncthreads();
  }

  if (MODE == 2) {
    // restage through LDS; write coalesced runs of <=OC consecutive floats
    float* ebuf = (float*)smem_raw;          // [32][132]
    const int c = tid & 127;
    const int rgrp = tid >> 7;               // 0..1
    const int n = (int)col0 + c;
    const int x = n / OC;
    const int o = o0 + (n - x * OC);
    const float bias = bias2[(((long long)z << 8) + x) * 128 + o];
    float* outp = Cf + z * sCz + (long long)x * (YY * LLn) + o;
    #pragma unroll
    for (int ch = 0; ch < 4; ch++) {
      #pragma unroll
      for (int tn = 0; tn < 4; tn++)
        #pragma unroll
        for (int e = 0; e < 4; e++)
          ebuf[((w >> 1) * 16 + fq * 4 + e) * 132 + wn + tn * 16 + fr] = acc[ch][tn][e];
      __syncthreads();
      const long long ybase = row0 + (long long)rgrp * 64 + ch * 16;
      #pragma unroll
      for (int r = 0; r < 16; r++)
        outp[(ybase + r) * LLn] = ebuf[(rgrp * 16 + r) * 132 + c] + bias;
      __syncthreads();
    }
  } else {
    const int er = fq * 4;
    #pragma unroll
    for (int tm = 0; tm < 4; tm++) {
      #pragma unroll
      for (int tn = 0; tn < 4; tn++) {
        const int rl = wm + tm * 16 + er;
        const long long col = col0 + wn + tn * 16 + fr;
        if (MODE == 0) {
          bf16_t* dst = Cb + z * sCz + col;
          #pragma unroll
          for (int r = 0; r < 4; r++)
            dst[(row0 + rl + r) * (long long)ldc] = (bf16_t)acc[tm][tn][r];
        } else {
          float* dst = Cf + z * sCz + col;
          #pragma unroll
          for (int r = 0; r < 4; r++)
            dst[(row0 + rl + r) * (long long)ldc] = acc[tm][tn][r];
        }
      }
    }
  }
}

// ---------------- loss ----------------

__device__ __forceinline__ float wave_max(float v) {
  #pragma unroll
  for (int off = 32; off > 0; off >>= 1) v = fmaxf(v, __shfl_xor(v, off));
  return v;
}
__device__ __forceinline__ float wave_sum(float v) {
  #pragma unroll
  for (int off = 32; off > 0; off >>= 1) v += __shfl_xor(v, off);
  return v;
}

__global__ void loss_kernel(const float* __restrict__ arc, const float* __restrict__ rel,
                            const int* __restrict__ la, const int* __restrict__ lr,
                            float* __restrict__ acc) {
  const int r = blockIdx.x;
  const int lane = threadIdx.x;    // 64
  const int lab = la[r];
  const float* ar = arc + (long long)r * YY;
  float v[8]; float m = -INFINITY;
  #pragma unroll
  for (int i = 0; i < 8; i++) { v[i] = ar[lane + 64 * i]; m = fmaxf(m, v[i]); }
  m = wave_max(m);
  float s = 0.f;
  #pragma unroll
  for (int i = 0; i < 8; i++) s += expf(v[i] - m);
  s = wave_sum(s);
  const float lse_a = m + logf(s);
  const int safe = lab < 0 ? 0 : (lab > YY - 1 ? YY - 1 : lab);
  const float* rr = rel + ((long long)r * YY + safe) * LLn;
  const float rv = (lane < LLn) ? rr[lane] : -INFINITY;
  const float m2 = wave_max(rv);
  const float s2 = wave_sum((lane < LLn) ? expf(rv - m2) : 0.f);
  const float lse_r = m2 + logf(s2);
  if (lane == 0 && lab != 0) {
    const float ll = (ar[safe] - lse_a) + (rr[lr[r]] - lse_r);
    atomicAdd(&acc[0], ll);
    atomicAdd(&acc[1], 1.f);
  }
}

__global__ void finalize(const float* __restrict__ acc, float* __restrict__ out) {
  out[0] = -acc[0] / acc[1];
}

// ---------------- launch ----------------

extern "C" void kernel_launch(void* const* d_in, const int* in_sizes, int n_in,
                              void* d_out, int out_size, void* d_ws, size_t ws_size,
                              hipStream_t stream) {
  (void)in_sizes; (void)n_in; (void)out_size;
  const float* hidden      = (const float*)d_in[0];
  const float* W_arc       = (const float*)d_in[1];
  const float* W_rel       = (const float*)d_in[2];
  const int* word_starts   = (const int*)d_in[3];
  const int* labels_arcs   = (const int*)d_in[4];
  const int* labels_rels   = (const int*)d_in[5];

  float* out = (float*)d_out;
  float* rel_out = out + 1;
  float* arc_out = rel_out + REL_ELEMS;

  char* ws = (char*)d_ws;
  int* n_valid = (int*)ws;                              // 16 ints
  float* lossacc = (float*)(ws + 64);                   // 2 floats
  bf16_t* xa_p  = (bf16_t*)(ws + 256);                  // [4096][800]
  bf16_t* yrb   = xa_p + (size_t)NB * SS * KP;          // [16][512][800]
  bf16_t* Wab   = yrb + (size_t)NB * YY * KP;           // [768][800]
  bf16_t* A1    = Wab + (size_t)HH * KP;                // [4096][768]
  bf16_t* Wb768 = A1 + (size_t)NB * SS * HH;            // [128][800]
  float*  bias2 = (float*)(Wb768 + (size_t)128 * KP);   // [4096][128] fp32
  bf16_t* Wbc   = (bf16_t*)(bias2 + (size_t)NB * SS * 128); // [OC][768][800]

  const size_t fixedB = 256 + 2 * ((size_t)NB * SS * KP + (size_t)NB * YY * KP +
                                   (size_t)HH * KP + (size_t)NB * SS * HH +
                                   (size_t)128 * KP) +
                        4 * (size_t)NB * SS * 128;
  const size_t perOC = 2 * ((size_t)JR * KP + (size_t)NB * SS * JR);
  int OC = 1;
  if (ws_size > fixedB + perOC) {
    const size_t m = (ws_size - fixedB) / perOC;
    OC = (m > (size_t)LLn) ? LLn : (int)m;
  }
  bf16_t* M_p = Wbc + (size_t)OC * JR * KP;             // [4096][OC][768]

  count_valid<<<NB, SS, 0, stream>>>(word_starts, n_valid, lossacc);
  hid_rows<<<NB * SS, 256, 0, stream>>>(hidden, yrb);
  build_deps<<<dim3(SS, NB), 256, 0, stream>>>(hidden, word_starts, n_valid, xa_p, yrb);
  conv_warc<<<dim3(25, 24), dim3(32, 8), 0, stream>>>(W_arc, Wab);
  build_wb768<<<128, 256, 0, stream>>>(W_rel, Wb768);

  // A1 = xa @ W_arc : [4096 x 768], K=800
  gemm_bt<0><<<dim3(6, 32, 1), 256, 0, stream>>>(xa_p, 0, KP, Wab, 0, KP, KP,
                                                 nullptr, A1, 0, HH, 0, 0, nullptr);
  // arc_preds = A1 . heads^T, K=768
  gemm_bt<1><<<dim3(4, 2, NB), 256, 0, stream>>>(A1, (long long)SS * HH, HH,
                                                 yrb, (long long)YY * KP, KP, HH,
                                                 arc_out, nullptr, (long long)SS * YY, YY,
                                                 0, 0, nullptr);
  // bias2 = xa @ Wb768^T : [4096 x 128], K=800
  gemm_bt<1><<<dim3(1, 32, 1), 256, 0, stream>>>(xa_p, 0, KP, Wb768, 0, KP, KP,
                                                 bias2, nullptr, 0, 128, 0, 0, nullptr);

  for (int o0 = 0; o0 < LLn; o0 += OC) {
    const int oc = (LLn - o0 < OC) ? (LLn - o0) : OC;
    conv_wrel<<<dim3(25, 24, oc), dim3(32, 8), 0, stream>>>(W_rel, Wbc, o0);
    // M[b,x,o,j<768] = xa . Wbc[o]^T, K=800
    gemm_bt<0><<<dim3(6, 32, oc), 256, 0, stream>>>(xa_p, 0, KP,
                                                    Wbc, (long long)JR * KP, KP, KP,
                                                    nullptr, M_p, JR, oc * JR, 0, 0, nullptr);
    // rel[b,x,y,o] = yrb[b,y,:768] . M[b,x,o,:] + bias2[b,x,o], K=768
    gemm_bt<2><<<dim3(2 * oc, 4, NB), 256, 0, stream>>>(yrb, (long long)YY * KP, KP,
                                                        M_p, (long long)SS * oc * JR, JR, JR,
                                                        rel_out, nullptr,
                                                        (long long)SS * YY * LLn, 0,
                                                        oc, o0, bias2);
  }

  loss_kernel<<<NB * SS, 64, 0, stream>>>(arc_out, rel_out, labels_arcs, labels_rels, lossacc);
  finalize<<<1, 1, 0, stream>>>(lossacc, out);
}